// Round 7
// baseline (271.879 us; speedup 1.0000x reference)
//
#include <hip/hip_runtime.h>

typedef float  f32x4  __attribute__((ext_vector_type(4)));
typedef short  bf16x8 __attribute__((ext_vector_type(8)));
typedef short  s16x4  __attribute__((ext_vector_type(4)));
typedef unsigned int u32x4 __attribute__((ext_vector_type(4)));

#define MFMA_BF16 __builtin_amdgcn_mfma_f32_16x16x32_bf16

__device__ __forceinline__ short f2bf(float f) {
  __bf16 h = (__bf16)f;
  return __builtin_bit_cast(short, h);
}

constexpr int S = 2048, D = 1024, H = 16, HD = 64;
constexpr int NT = S / 64;                 // 32 kv tiles total
constexpr float SCALE = 0.125f;            // 1/sqrt(64)
constexpr float L2E = 1.44269504f;
constexpr float SL = SCALE * L2E;          // logits -> log2 domain in one mul

#define GLDS16(g, l) __builtin_amdgcn_global_load_lds( \
    (const __attribute__((address_space(1))) unsigned*)(g), \
    (__attribute__((address_space(3))) unsigned*)(l), 16, 0, 0)

#define WAITV(n) asm volatile("s_waitcnt vmcnt(" #n ")" ::: "memory")
#define SBAR()   __builtin_amdgcn_s_barrier()

// ---------------------------------------------------------------------------
// K/V prep: f32 [B,S,D] head-slices -> interleaved bf16 fragment-major tiles.
// Per (b,h,kv-tile): 16 frags of 512 shorts: f<8 = K frag (kk*4+mf),
// f>=8 = V^T frag (kk*4+of). Tile block = 8192 shorts (16KB).
// ---------------------------------------------------------------------------
__global__ __launch_bounds__(256)
void kv_prep(const float* __restrict__ Kg, const float* __restrict__ Vg,
             short* __restrict__ KVb) {
  const int tile = blockIdx.x, h = blockIdx.y, b = blockIdx.z;
  const int t = threadIdx.x, lane = t & 63, w = t >> 6;
  const int lg = lane >> 4, lm = lane & 15;
  __shared__ short kt[64 * 68], vt[64 * 68];
  const float* kp = Kg + ((size_t)(b * S + tile * 64)) * D + h * HD;
  const float* vp = Vg + ((size_t)(b * S + tile * 64)) * D + h * HD;
  #pragma unroll
  for (int i = 0; i < 4; ++i) {
    int idx = i * 256 + t, r = idx >> 4, c4 = (idx & 15) * 4;
    float4 k4 = *(const float4*)(kp + (size_t)r * D + c4);
    s16x4 ks; ks[0]=f2bf(k4.x); ks[1]=f2bf(k4.y); ks[2]=f2bf(k4.z); ks[3]=f2bf(k4.w);
    *(s16x4*)&kt[r * 68 + c4] = ks;
    float4 v4 = *(const float4*)(vp + (size_t)r * D + c4);
    s16x4 vs; vs[0]=f2bf(v4.x); vs[1]=f2bf(v4.y); vs[2]=f2bf(v4.z); vs[3]=f2bf(v4.w);
    *(s16x4*)&vt[r * 68 + c4] = vs;
  }
  __syncthreads();
  const size_t obase = ((size_t)((b * H + h) * NT + tile)) * 8192;
  #pragma unroll
  for (int j = 0; j < 2; ++j) {          // K frags f = kk*4+mf
    int f = w + j * 4, kk = f >> 2, mf = f & 3;
    int row = mf * 16 + lm, col = kk * 32 + lg * 4;
    s16x4 c0 = *(const s16x4*)&kt[row * 68 + col];
    s16x4 c1 = *(const s16x4*)&kt[row * 68 + col + 16];
    bf16x8 a;
    a[0]=c0[0]; a[1]=c0[1]; a[2]=c0[2]; a[3]=c0[3];
    a[4]=c1[0]; a[5]=c1[1]; a[6]=c1[2]; a[7]=c1[3];
    *(bf16x8*)&KVb[obase + (size_t)(f * 64 + lane) * 8] = a;
  }
  #pragma unroll
  for (int j = 0; j < 2; ++j) {          // V^T frags f = 8 + kk*4+of
    int fv = w + j * 4, kk = fv >> 2, of = fv & 3;
    int col = of * 16 + lm;
    bf16x8 a;
    #pragma unroll
    for (int half = 0; half < 2; ++half)
      #pragma unroll
      for (int e = 0; e < 4; ++e)
        a[half * 4 + e] = vt[(kk * 32 + lg * 4 + half * 16 + e) * 68 + col];
    *(bf16x8*)&KVb[obase + (size_t)((8 + fv) * 64 + lane) * 8] = a;
  }
}

// ---------------------------------------------------------------------------
// Flash attention, split-KV<SPLIT>: block = (b, h, 128 q-rows, kv-slice).
// 4 waves x 32 q/wave; bias loads directly as QK^T C-init; counted vmcnt.
// Writes partial O^T (f32) + m,l; combine kernel merges slices.
// Grid = 512*SPLIT -> 8 blocks/CU dispatched at SPLIT=4 (5 resident, LDS cap).
// ---------------------------------------------------------------------------
template <int SPLIT>
__global__ __launch_bounds__(256, 5)
void attn_fused(const float* __restrict__ Qg, const float* __restrict__ Bg,
                const short* __restrict__ KVb,
                float* __restrict__ OP, float* __restrict__ ML) {
  constexpr int NTH = NT / SPLIT;
  __shared__ __attribute__((aligned(16))) short smem[16384]; // 2 x 16KB tile bufs
  const int bid = blockIdx.x;
  // c = bid&7 ~ XCD: hosts h = {2c, 2c+1}; b/slice vary within an XCD's
  // slots so bias & KV tiles stay L2-shared.
  const int c = bid & 7, g = bid >> 3;
  const int qb = g & 15, z = g >> 4;
  const int h = (c << 1) | (z & 1);
  const int b = (z >> 1) & 1;
  const int half = z >> 2;                     // kv-slice in [0, SPLIT)
  const int q0 = qb * 128;
  const int t = threadIdx.x, lane = t & 63, w = t >> 6;
  const int lg = lane >> 4, lm = lane & 15;

  // Q frags: fq covers query col q0 + w*32 + fq*16 + lm
  bf16x8 qf[2][2];
  #pragma unroll
  for (int fq = 0; fq < 2; ++fq) {
    const float* qp = Qg + ((size_t)(b * S + q0 + w * 32 + fq * 16 + lm)) * D + h * HD;
    #pragma unroll
    for (int kk = 0; kk < 2; ++kk)
      #pragma unroll
      for (int j = 0; j < 8; ++j)
        qf[fq][kk][j] = f2bf(qp[kk * 32 + (j >> 2) * 16 + lg * 4 + (j & 3)]);
  }

  const short* KVt = KVb + ((size_t)((b * H + h) * NT + half * NTH)) * 8192;
  const float* bp = Bg + ((size_t)(h * S + q0 + w * 32 + lm)) * S + half * (NTH * 64) + lg * 4;

  const f32x4 zero4 = {0.f, 0.f, 0.f, 0.f};
  f32x4 o[2][4];
  #pragma unroll
  for (int fq = 0; fq < 2; ++fq)
    #pragma unroll
    for (int i = 0; i < 4; ++i) o[fq][i] = zero4;
  float M[2] = {-__builtin_inff(), -__builtin_inff()};
  float L[2] = {0.f, 0.f};
  f32x4 sacc[2][4];          // bias(t) -> logits(t) -> p(t), time-shared

#define STAGE(tile, buf)                                                \
  {                                                                     \
    const short* kvg_ = KVt + (size_t)(tile) * 8192;                    \
    _Pragma("unroll")                                                   \
    for (int f_ = 0; f_ < 4; ++f_) {                                    \
      int fr_ = w * 4 + f_;                                             \
      GLDS16(kvg_ + (size_t)(fr_ * 64 + lane) * 8, (buf) + fr_ * 512);  \
    }                                                                   \
  }

  // bias straight into sacc (C-init): 8 dwordx4/lane
#define BLOAD(tile)                                                     \
  {                                                                     \
    _Pragma("unroll")                                                   \
    for (int fq_ = 0; fq_ < 2; ++fq_)                                   \
      _Pragma("unroll")                                                 \
      for (int mf_ = 0; mf_ < 4; ++mf_)                                 \
        sacc[fq_][mf_] = *(const f32x4*)(bp + (size_t)fq_ * 16 * S +    \
                                         (size_t)(tile) * 64 + mf_ * 16); \
  }

  STAGE(0, smem);            // 4 vm (oldest)
  BLOAD(0);                  // 8 vm

  for (int tt = 0; tt < NTH; ++tt) {
    SBAR();
    if (tt < NTH - 1) {
      STAGE(tt + 1, smem + ((tt + 1) & 1) * 8192);
      WAITV(12);             // retire STAGE(tt); leave BLOAD(tt)+STAGE(tt+1)
    } else {
      WAITV(8);              // retire STAGE(tt); leave BLOAD(tt)
    }
    SBAR();
    const short* buf = smem + (tt & 1) * 8192;

    // QK^T, C-in = bias (compiler inserts the fine vmcnt for sacc uses)
    __builtin_amdgcn_s_setprio(1);
    #pragma unroll
    for (int kk = 0; kk < 2; ++kk)
      #pragma unroll
      for (int mf = 0; mf < 4; ++mf) {
        bf16x8 a = *(const bf16x8*)&buf[(kk * 4 + mf) * 512 + lane * 8];
        sacc[0][mf] = MFMA_BF16(a, qf[0][kk], sacc[0][mf], 0, 0, 0);
        sacc[1][mf] = MFMA_BF16(a, qf[1][kk], sacc[1][mf], 0, 0, 0);
      }
    __builtin_amdgcn_s_setprio(0);

    // online softmax in log2 domain, in place in sacc
    float tmax[2] = {-__builtin_inff(), -__builtin_inff()};
    #pragma unroll
    for (int fq = 0; fq < 2; ++fq)
      #pragma unroll
      for (int mf = 0; mf < 4; ++mf)
        #pragma unroll
        for (int j = 0; j < 4; ++j) {
          float tv = sacc[fq][mf][j] * SL;
          sacc[fq][mf][j] = tv;
          tmax[fq] = fmaxf(tmax[fq], tv);
        }
    #pragma unroll
    for (int fq = 0; fq < 2; ++fq) {
      tmax[fq] = fmaxf(tmax[fq], __shfl_xor(tmax[fq], 16, 64));
      tmax[fq] = fmaxf(tmax[fq], __shfl_xor(tmax[fq], 32, 64));
    }
    const int skip = (tmax[0] <= M[0]) && (tmax[1] <= M[1]);
    if (!__all(skip)) {
      #pragma unroll
      for (int fq = 0; fq < 2; ++fq) {
        float Mn = fmaxf(M[fq], tmax[fq]);
        float alpha = exp2f(M[fq] - Mn);
        #pragma unroll
        for (int of = 0; of < 4; ++of) {
          o[fq][of][0] *= alpha; o[fq][of][1] *= alpha;
          o[fq][of][2] *= alpha; o[fq][of][3] *= alpha;
        }
        L[fq] *= alpha;
        M[fq] = Mn;
      }
    }
    #pragma unroll
    for (int fq = 0; fq < 2; ++fq) {
      float psum = 0.f;
      #pragma unroll
      for (int mf = 0; mf < 4; ++mf)
        #pragma unroll
        for (int j = 0; j < 4; ++j) {
          float e = exp2f(sacc[fq][mf][j] - M[fq]);
          sacc[fq][mf][j] = e;
          psum += e;
        }
      psum += __shfl_xor(psum, 16, 64);
      psum += __shfl_xor(psum, 32, 64);
      L[fq] += psum;
    }
    bf16x8 pb[2][2];
    #pragma unroll
    for (int fq = 0; fq < 2; ++fq)
      #pragma unroll
      for (int kk = 0; kk < 2; ++kk)
        #pragma unroll
        for (int j = 0; j < 8; ++j)
          pb[fq][kk][j] = f2bf(sacc[fq][kk * 2 + (j >> 2)][j & 3]);

    if (tt < NTH - 1) BLOAD(tt + 1);   // next bias into freed sacc regs

    __builtin_amdgcn_s_setprio(1);
    #pragma unroll
    for (int kk = 0; kk < 2; ++kk)
      #pragma unroll
      for (int of = 0; of < 4; ++of) {
        bf16x8 a = *(const bf16x8*)&buf[4096 + (kk * 4 + of) * 512 + lane * 8];
        o[0][of] = MFMA_BF16(a, pb[0][kk], o[0][of], 0, 0, 0);
        o[1][of] = MFMA_BF16(a, pb[1][kk], o[1][of], 0, 0, 0);
      }
    __builtin_amdgcn_s_setprio(0);
  }

  // write partial O^T [128 q][64 d] f32 + m,l (no normalize, no transpose)
  const int p = ((b * H + h) << 4) | qb;
  float* opb = OP + ((size_t)(half * 512 + p)) * 8192;
  #pragma unroll
  for (int fq = 0; fq < 2; ++fq)
    #pragma unroll
    for (int of = 0; of < 4; ++of)
      *(f32x4*)&opb[(w * 32 + fq * 16 + lm) * 64 + of * 16 + lg * 4] = o[fq][of];
  float* mlb = ML + ((size_t)(half * 512 + p)) * 256;
  if (lane < 16) {
    mlb[w * 32 + lm]        = M[0];
    mlb[w * 32 + 16 + lm]   = M[1];
    mlb[128 + w * 32 + lm]      = L[0];
    mlb[128 + w * 32 + 16 + lm] = L[1];
  }
#undef STAGE
#undef BLOAD
}

// ---------------------------------------------------------------------------
// Combine SPLIT kv-slice partials -> comb bf16 [B*S][D]
// ---------------------------------------------------------------------------
template <int SPLIT>
__global__ __launch_bounds__(256)
void combine(const float* __restrict__ OP, const float* __restrict__ ML,
             short* __restrict__ comb) {
  const int p = blockIdx.x;                 // 512 (b,h,qb) groups
  const int b = p >> 8, h = (p >> 4) & 15, qb = p & 15;
  const int t = threadIdx.x;
  #pragma unroll
  for (int k = 0; k < 8; ++k) {
    int e = (k * 256 + t) * 4;
    int q = e >> 6, d = e & 63;
    float ms[SPLIT], ls[SPLIT];
    float m = -__builtin_inff();
    #pragma unroll
    for (int s = 0; s < SPLIT; ++s) {
      const float* mlb = ML + (size_t)(s * 512 + p) * 256;
      ms[s] = mlb[q];
      ls[s] = mlb[128 + q];
      m = fmaxf(m, ms[s]);
    }
    float denom = 0.f;
    f32x4 acc = {0.f, 0.f, 0.f, 0.f};
    #pragma unroll
    for (int s = 0; s < SPLIT; ++s) {
      float a = exp2f(ms[s] - m);
      denom += ls[s] * a;
      f32x4 v = *(const f32x4*)&OP[(size_t)(s * 512 + p) * 8192 + e];
      acc[0] += v[0] * a; acc[1] += v[1] * a;
      acc[2] += v[2] * a; acc[3] += v[3] * a;
    }
    float inv = 1.f / denom;
    s16x4 r;
    #pragma unroll
    for (int j = 0; j < 4; ++j) r[j] = f2bf(acc[j] * inv);
    *(s16x4*)&comb[((size_t)(b * S + qb * 128 + q)) * D + h * HD + d] = r;
  }
}

// ---------------------------------------------------------------------------
// w_out [k][n] f32 -> Wt [n][k] bf16
// ---------------------------------------------------------------------------
__global__ __launch_bounds__(256)
void wt_kernel(const float* __restrict__ W, short* __restrict__ Wt) {
  __shared__ __attribute__((aligned(16))) short tile[64 * 72];
  const int n0 = blockIdx.x * 64, k0 = blockIdx.y * 64;
  const int t = threadIdx.x;
  #pragma unroll
  for (int i = 0; i < 4; ++i) {
    int idx = i * 256 + t;
    int r  = idx >> 4, c4 = (idx & 15) * 4;
    float4 wv = *(const float4*)(W + (size_t)(k0 + r) * D + n0 + c4);
    tile[(c4 + 0) * 72 + r] = f2bf(wv.x);
    tile[(c4 + 1) * 72 + r] = f2bf(wv.y);
    tile[(c4 + 2) * 72 + r] = f2bf(wv.z);
    tile[(c4 + 3) * 72 + r] = f2bf(wv.w);
  }
  __syncthreads();
  #pragma unroll
  for (int it = 0; it < 2; ++it) {
    int idx = it * 256 + t;
    int r = idx >> 3, seg = idx & 7;
    u32x4 u = *(const u32x4*)&tile[r * 72 + seg * 8];
    *(u32x4*)&Wt[(size_t)(n0 + r) * D + k0 + seg * 8] = u;
  }
}

// ---------------------------------------------------------------------------
// proj: C[4096,1024] f32 = A bf16 * Wt^T. 128x64 tile, counted-vmcnt,
// both-sides 16B-unit XOR swizzle on LDS.
// ---------------------------------------------------------------------------
__device__ __forceinline__ bf16x8 ld_frag_swz(const short* base, int row, int kk, int lg) {
  const char* rp = (const char*)base + row * 128 + (lg & 1) * 8;
  int u0 = kk * 4 + (lg >> 1);
  int f  = row & 7;
  s16x4 c0 = *(const s16x4*)(rp + ((u0 ^ f) << 4));
  s16x4 c1 = *(const s16x4*)(rp + (((u0 + 2) ^ f) << 4));
  bf16x8 a;
  a[0]=c0[0]; a[1]=c0[1]; a[2]=c0[2]; a[3]=c0[3];
  a[4]=c1[0]; a[5]=c1[1]; a[6]=c1[2]; a[7]=c1[3];
  return a;
}

__global__ __launch_bounds__(256, 2)
void proj_gemm(const short* __restrict__ A, const short* __restrict__ Bt,
               float* __restrict__ C) {
  __shared__ __attribute__((aligned(16))) short a_lds[2][8192];
  __shared__ __attribute__((aligned(16))) short b_lds[2][4096];
  const int m0 = blockIdx.x * 128, n0 = blockIdx.y * 64;
  const int t = threadIdx.x, lane = t & 63, w = t >> 6;
  const int lg = lane >> 4, lm = lane & 15;
  const int srow = lane >> 3;
  const int sunit = (lane & 7) ^ srow;

  const f32x4 zero4 = {0.f, 0.f, 0.f, 0.f};
  f32x4 acc[2][4];
  #pragma unroll
  for (int i = 0; i < 2; ++i)
    #pragma unroll
    for (int j = 0; j < 4; ++j) acc[i][j] = zero4;

#define PSTAGE(ks, ab, bb)                                                  \
  {                                                                         \
    const short* ag_ = A  + (size_t)m0 * D + (ks) * 64;                     \
    const short* bg_ = Bt + (size_t)n0 * D + (ks) * 64;                     \
    _Pragma("unroll")                                                       \
    for (int i_ = 0; i_ < 4; ++i_) {                                        \
      int j_ = w * 4 + i_;                                                  \
      GLDS16(ag_ + (size_t)(j_ * 8 + srow) * D + sunit * 8, (ab) + j_ * 512); \
    }                                                                       \
    _Pragma("unroll")                                                       \
    for (int i_ = 0; i_ < 2; ++i_) {                                        \
      int j_ = w * 2 + i_;                                                  \
      GLDS16(bg_ + (size_t)(j_ * 8 + srow) * D + sunit * 8, (bb) + j_ * 512); \
    }                                                                       \
  }

#define PCOMPUTE(ab, bb)                                                    \
  {                                                                         \
    _Pragma("unroll")                                                       \
    for (int kk = 0; kk < 2; ++kk) {                                        \
      bf16x8 af0 = ld_frag_swz(ab, w * 32 + lm, kk, lg);                    \
      bf16x8 af1 = ld_frag_swz(ab, w * 32 + 16 + lm, kk, lg);               \
      bf16x8 bf0 = ld_frag_swz(bb, lm, kk, lg);                             \
      bf16x8 bf1 = ld_frag_swz(bb, 16 + lm, kk, lg);                        \
      bf16x8 bf2 = ld_frag_swz(bb, 32 + lm, kk, lg);                        \
      bf16x8 bf3 = ld_frag_swz(bb, 48 + lm, kk, lg);                        \
      __builtin_amdgcn_s_setprio(1);                                        \
      acc[0][0] = MFMA_BF16(af0, bf0, acc[0][0], 0, 0, 0);                  \
      acc[0][1] = MFMA_BF16(af0, bf1, acc[0][1], 0, 0, 0);                  \
      acc[0][2] = MFMA_BF16(af0, bf2, acc[0][2], 0, 0, 0);                  \
      acc[0][3] = MFMA_BF16(af0, bf3, acc[0][3], 0, 0, 0);                  \
      acc[1][0] = MFMA_BF16(af1, bf0, acc[1][0], 0, 0, 0);                  \
      acc[1][1] = MFMA_BF16(af1, bf1, acc[1][1], 0, 0, 0);                  \
      acc[1][2] = MFMA_BF16(af1, bf2, acc[1][2], 0, 0, 0);                  \
      acc[1][3] = MFMA_BF16(af1, bf3, acc[1][3], 0, 0, 0);                  \
      __builtin_amdgcn_s_setprio(0);                                        \
    }                                                                       \
  }

  PSTAGE(0, a_lds[0], b_lds[0]);
  for (int ks = 0; ks < 16; ks += 2) {
    SBAR();
    PSTAGE(ks + 1, a_lds[1], b_lds[1]);
    WAITV(6);
    SBAR();
    PCOMPUTE(a_lds[0], b_lds[0]);
    SBAR();
    if (ks + 2 < 16) {
      PSTAGE(ks + 2, a_lds[0], b_lds[0]);
      WAITV(6);
    } else {
      WAITV(0);
    }
    SBAR();
    PCOMPUTE(a_lds[1], b_lds[1]);
  }

  #pragma unroll
  for (int mf = 0; mf < 2; ++mf)
    #pragma unroll
    for (int j = 0; j < 4; ++j)
      #pragma unroll
      for (int nf = 0; nf < 4; ++nf)
        C[(size_t)(m0 + w * 32 + mf * 16 + lg * 4 + j) * D +
          n0 + nf * 16 + lm] = acc[mf][nf][j];
#undef PSTAGE
#undef PCOMPUTE
}

extern "C" void kernel_launch(void* const* d_in, const int* in_sizes, int n_in,
                              void* d_out, int out_size, void* d_ws, size_t ws_size,
                              hipStream_t stream) {
  const float* Qg = (const float*)d_in[0];
  const float* Kg = (const float*)d_in[1];
  const float* Vg = (const float*)d_in[2];
  const float* Bg = (const float*)d_in[3];
  const float* Wg = (const float*)d_in[4];
  float* out = (float*)d_out;

  short* comb = (short*)d_ws;                          //  8 MB bf16 [4096][1024]
  short* Wt   = comb + (size_t)4096 * 1024;            //  2 MB bf16 [1024][1024]
  short* KVb  = Wt   + (size_t)1024 * 1024;            // 16 MB interleaved K/V frags
  float* OP   = (float*)(KVb + (size_t)2 * H * NT * 8192); // partial O^T

  // split-4 needs 27.3 + 67.1 + 2.1 = 96.5 MB of ws; fall back to split-2
  const size_t base = (size_t)27262976;
  const size_t need4 = base + (size_t)4 * 512 * 8192 * 4 + (size_t)4 * 512 * 256 * 4;

  kv_prep<<<dim3(NT, H, 2), 256, 0, stream>>>(Kg, Vg, KVb);
  wt_kernel<<<dim3(D / 64, D / 64), 256, 0, stream>>>(Wg, Wt);
  if (ws_size >= need4) {
    float* ML = OP + (size_t)4 * 512 * 8192;
    attn_fused<4><<<dim3(2048), 256, 0, stream>>>(Qg, Bg, KVb, OP, ML);
    combine<4><<<dim3(512), 256, 0, stream>>>(OP, ML, comb);
  } else {
    float* ML = OP + (size_t)2 * 512 * 8192;
    attn_fused<2><<<dim3(1024), 256, 0, stream>>>(Qg, Bg, KVb, OP, ML);
    combine<2><<<dim3(512), 256, 0, stream>>>(OP, ML, comb);
  }
  proj_gemm<<<dim3(32, 16), 256, 0, stream>>>(comb, Wt, out);
}

// Round 8
// 149.623 us; speedup vs baseline: 1.8171x; 1.8171x over previous
//
#include <hip/hip_runtime.h>

typedef float  f32x4  __attribute__((ext_vector_type(4)));
typedef short  bf16x8 __attribute__((ext_vector_type(8)));
typedef short  s16x4  __attribute__((ext_vector_type(4)));
typedef unsigned int u32x4 __attribute__((ext_vector_type(4)));

#define MFMA_BF16 __builtin_amdgcn_mfma_f32_16x16x32_bf16

__device__ __forceinline__ short f2bf(float f) {
  __bf16 h = (__bf16)f;
  return __builtin_bit_cast(short, h);
}

constexpr int S = 2048, D = 1024, H = 16, HD = 64;
constexpr int NT = S / 64;                 // 32 kv tiles total
constexpr int NTH = NT / 2;                // 16 tiles per kv-half
constexpr float SCALE = 0.125f;            // 1/sqrt(64)
constexpr float L2E = 1.44269504f;
constexpr float SL = SCALE * L2E;          // logits -> log2 domain in one mul

#define GLDS16(g, l) __builtin_amdgcn_global_load_lds( \
    (const __attribute__((address_space(1))) unsigned*)(g), \
    (__attribute__((address_space(3))) unsigned*)(l), 16, 0, 0)

#define WAITV(n) asm volatile("s_waitcnt vmcnt(" #n ")" ::: "memory")
#define SBAR()   __builtin_amdgcn_s_barrier()

// ---------------------------------------------------------------------------
// K/V prep: f32 [B,S,D] head-slices -> interleaved bf16 fragment-major tiles.
// Per (b,h,kv-tile): 16 frags of 512 shorts: f<8 = K frag (kk*4+mf),
// f>=8 = V^T frag (kk*4+of). Tile block = 8192 shorts (16KB).
// ---------------------------------------------------------------------------
__global__ __launch_bounds__(256)
void kv_prep(const float* __restrict__ Kg, const float* __restrict__ Vg,
             short* __restrict__ KVb) {
  const int tile = blockIdx.x, h = blockIdx.y, b = blockIdx.z;
  const int t = threadIdx.x, lane = t & 63, w = t >> 6;
  const int lg = lane >> 4, lm = lane & 15;
  __shared__ short kt[64 * 68], vt[64 * 68];
  const float* kp = Kg + ((size_t)(b * S + tile * 64)) * D + h * HD;
  const float* vp = Vg + ((size_t)(b * S + tile * 64)) * D + h * HD;
  #pragma unroll
  for (int i = 0; i < 4; ++i) {
    int idx = i * 256 + t, r = idx >> 4, c4 = (idx & 15) * 4;
    float4 k4 = *(const float4*)(kp + (size_t)r * D + c4);
    s16x4 ks; ks[0]=f2bf(k4.x); ks[1]=f2bf(k4.y); ks[2]=f2bf(k4.z); ks[3]=f2bf(k4.w);
    *(s16x4*)&kt[r * 68 + c4] = ks;
    float4 v4 = *(const float4*)(vp + (size_t)r * D + c4);
    s16x4 vs; vs[0]=f2bf(v4.x); vs[1]=f2bf(v4.y); vs[2]=f2bf(v4.z); vs[3]=f2bf(v4.w);
    *(s16x4*)&vt[r * 68 + c4] = vs;
  }
  __syncthreads();
  const size_t obase = ((size_t)((b * H + h) * NT + tile)) * 8192;
  #pragma unroll
  for (int j = 0; j < 2; ++j) {          // K frags f = kk*4+mf
    int f = w + j * 4, kk = f >> 2, mf = f & 3;
    int row = mf * 16 + lm, col = kk * 32 + lg * 4;
    s16x4 c0 = *(const s16x4*)&kt[row * 68 + col];
    s16x4 c1 = *(const s16x4*)&kt[row * 68 + col + 16];
    bf16x8 a;
    a[0]=c0[0]; a[1]=c0[1]; a[2]=c0[2]; a[3]=c0[3];
    a[4]=c1[0]; a[5]=c1[1]; a[6]=c1[2]; a[7]=c1[3];
    *(bf16x8*)&KVb[obase + (size_t)(f * 64 + lane) * 8] = a;
  }
  #pragma unroll
  for (int j = 0; j < 2; ++j) {          // V^T frags f = 8 + kk*4+of
    int fv = w + j * 4, kk = fv >> 2, of = fv & 3;
    int col = of * 16 + lm;
    bf16x8 a;
    #pragma unroll
    for (int half = 0; half < 2; ++half)
      #pragma unroll
      for (int e = 0; e < 4; ++e)
        a[half * 4 + e] = vt[(kk * 32 + lg * 4 + half * 16 + e) * 68 + col];
    *(bf16x8*)&KVb[obase + (size_t)((8 + fv) * 64 + lane) * 8] = a;
  }
}

// ---------------------------------------------------------------------------
// Flash attention, split-KV(2): 8-wave 512-thread blocks, 32 q/wave.
// Grid 512 = 2 blocks/CU (16 waves/CU). Bias loads directly as QK^T C-init;
// counted vmcnt (each wave: 2 gload_lds + 8 bias dwordx4 per tile).
// Partial O stored LANE-MAJOR (coalesced); combine fixes layout via LDS.
// ---------------------------------------------------------------------------
__global__ __launch_bounds__(512, 4)
void attn_fused(const float* __restrict__ Qg, const float* __restrict__ Bg,
                const short* __restrict__ KVb,
                float* __restrict__ OP, float* __restrict__ ML) {
  __shared__ __attribute__((aligned(16))) short smem[16384]; // 2 x 16KB tile bufs
  const int bid = blockIdx.x;
  // c = bid&7 ~ XCD: hosts h = {2c,2c+1} (K/V ~2MB, L2-resident); b/half vary
  // within an XCD's slots so bias tiles are L2-shared across the b-pair.
  const int c = bid & 7, g = bid >> 3;
  const int qb = g & 7, z = g >> 3;            // z: 3 bits
  const int h = (c << 1) | (z & 1);
  const int b = (z >> 1) & 1;
  const int half = z >> 2;                     // kv-half
  const int q0 = qb * 256;
  const int t = threadIdx.x, lane = t & 63, w = t >> 6;   // w in [0,8)
  const int lg = lane >> 4, lm = lane & 15;

  // Q frags: fq covers query col q0 + w*32 + fq*16 + lm
  bf16x8 qf[2][2];
  #pragma unroll
  for (int fq = 0; fq < 2; ++fq) {
    const float* qp = Qg + ((size_t)(b * S + q0 + w * 32 + fq * 16 + lm)) * D + h * HD;
    #pragma unroll
    for (int kk = 0; kk < 2; ++kk)
      #pragma unroll
      for (int j = 0; j < 8; ++j)
        qf[fq][kk][j] = f2bf(qp[kk * 32 + (j >> 2) * 16 + lg * 4 + (j & 3)]);
  }

  const short* KVt = KVb + ((size_t)((b * H + h) * NT + half * NTH)) * 8192;
  const float* bp = Bg + ((size_t)(h * S + q0 + w * 32 + lm)) * S + half * (NTH * 64) + lg * 4;

  const f32x4 zero4 = {0.f, 0.f, 0.f, 0.f};
  f32x4 o[2][4];
  #pragma unroll
  for (int fq = 0; fq < 2; ++fq)
    #pragma unroll
    for (int i = 0; i < 4; ++i) o[fq][i] = zero4;
  float M[2] = {-__builtin_inff(), -__builtin_inff()};
  float L[2] = {0.f, 0.f};
  f32x4 sacc[2][4];          // bias(t) -> logits(t) -> p(t), time-shared

  // wave w stages frags {2w, 2w+1} of the 16-frag tile: 2 gload_lds
#define STAGE(tile, buf)                                                \
  {                                                                     \
    const short* kvg_ = KVt + (size_t)(tile) * 8192;                    \
    _Pragma("unroll")                                                   \
    for (int f_ = 0; f_ < 2; ++f_) {                                    \
      int fr_ = w * 2 + f_;                                             \
      GLDS16(kvg_ + (size_t)(fr_ * 64 + lane) * 8, (buf) + fr_ * 512);  \
    }                                                                   \
  }

  // bias straight into sacc (C-init): 8 dwordx4/lane
#define BLOAD(tile)                                                     \
  {                                                                     \
    _Pragma("unroll")                                                   \
    for (int fq_ = 0; fq_ < 2; ++fq_)                                   \
      _Pragma("unroll")                                                 \
      for (int mf_ = 0; mf_ < 4; ++mf_)                                 \
        sacc[fq_][mf_] = *(const f32x4*)(bp + (size_t)fq_ * 16 * S +    \
                                         (size_t)(tile) * 64 + mf_ * 16); \
  }

  STAGE(0, smem);            // 2 vm (oldest)
  BLOAD(0);                  // 8 vm

  for (int tt = 0; tt < NTH; ++tt) {
    SBAR();
    if (tt < NTH - 1) {
      STAGE(tt + 1, smem + ((tt + 1) & 1) * 8192);
      WAITV(10);             // retire STAGE(tt); leave BLOAD(tt)8+STAGE(tt+1)2
    } else {
      WAITV(8);              // retire STAGE(tt); leave BLOAD(tt)8
    }
    SBAR();
    const short* buf = smem + (tt & 1) * 8192;

    // QK^T, C-in = bias (compiler inserts the fine vmcnt for sacc uses)
    __builtin_amdgcn_s_setprio(1);
    #pragma unroll
    for (int kk = 0; kk < 2; ++kk)
      #pragma unroll
      for (int mf = 0; mf < 4; ++mf) {
        bf16x8 a = *(const bf16x8*)&buf[(kk * 4 + mf) * 512 + lane * 8];
        sacc[0][mf] = MFMA_BF16(a, qf[0][kk], sacc[0][mf], 0, 0, 0);
        sacc[1][mf] = MFMA_BF16(a, qf[1][kk], sacc[1][mf], 0, 0, 0);
      }
    __builtin_amdgcn_s_setprio(0);

    // online softmax in log2 domain, in place in sacc
    float tmax[2] = {-__builtin_inff(), -__builtin_inff()};
    #pragma unroll
    for (int fq = 0; fq < 2; ++fq)
      #pragma unroll
      for (int mf = 0; mf < 4; ++mf)
        #pragma unroll
        for (int j = 0; j < 4; ++j) {
          float tv = sacc[fq][mf][j] * SL;
          sacc[fq][mf][j] = tv;
          tmax[fq] = fmaxf(tmax[fq], tv);
        }
    #pragma unroll
    for (int fq = 0; fq < 2; ++fq) {
      tmax[fq] = fmaxf(tmax[fq], __shfl_xor(tmax[fq], 16, 64));
      tmax[fq] = fmaxf(tmax[fq], __shfl_xor(tmax[fq], 32, 64));
    }
    const int skip = (tmax[0] <= M[0]) && (tmax[1] <= M[1]);
    if (!__all(skip)) {
      #pragma unroll
      for (int fq = 0; fq < 2; ++fq) {
        float Mn = fmaxf(M[fq], tmax[fq]);
        float alpha = exp2f(M[fq] - Mn);
        #pragma unroll
        for (int of = 0; of < 4; ++of) {
          o[fq][of][0] *= alpha; o[fq][of][1] *= alpha;
          o[fq][of][2] *= alpha; o[fq][of][3] *= alpha;
        }
        L[fq] *= alpha;
        M[fq] = Mn;
      }
    }
    #pragma unroll
    for (int fq = 0; fq < 2; ++fq) {
      float psum = 0.f;
      #pragma unroll
      for (int mf = 0; mf < 4; ++mf)
        #pragma unroll
        for (int j = 0; j < 4; ++j) {
          float e = exp2f(sacc[fq][mf][j] - M[fq]);
          sacc[fq][mf][j] = e;
          psum += e;
        }
      psum += __shfl_xor(psum, 16, 64);
      psum += __shfl_xor(psum, 32, 64);
      L[fq] += psum;
    }
    bf16x8 pb[2][2];
    #pragma unroll
    for (int fq = 0; fq < 2; ++fq)
      #pragma unroll
      for (int kk = 0; kk < 2; ++kk)
        #pragma unroll
        for (int j = 0; j < 8; ++j)
          pb[fq][kk][j] = f2bf(sacc[fq][kk * 2 + (j >> 2)][j & 3]);

    if (tt < NTH - 1) BLOAD(tt + 1);   // next bias into freed sacc regs

    __builtin_amdgcn_s_setprio(1);
    #pragma unroll
    for (int kk = 0; kk < 2; ++kk)
      #pragma unroll
      for (int of = 0; of < 4; ++of) {
        bf16x8 a = *(const bf16x8*)&buf[4096 + (kk * 4 + of) * 512 + lane * 8];
        o[0][of] = MFMA_BF16(a, pb[0][kk], o[0][of], 0, 0, 0);
        o[1][of] = MFMA_BF16(a, pb[1][kk], o[1][of], 0, 0, 0);
      }
    __builtin_amdgcn_s_setprio(0);
  }

  // partial O store, LANE-MAJOR (fully coalesced): per (half,p,w):
  // frag f = fq*4+of at float offset f*256 + lane*4
  const int p = ((b * H + h) << 3) | qb;       // 0..255
  float* opb = OP + ((size_t)(half * 256 + p)) * 16384 + w * 2048;
  #pragma unroll
  for (int fq = 0; fq < 2; ++fq)
    #pragma unroll
    for (int of = 0; of < 4; ++of)
      *(f32x4*)&opb[(fq * 4 + of) * 256 + lane * 4] = o[fq][of];
  float* mlb = ML + ((size_t)(half * 256 + p)) * 512;
  if (lane < 16) {
    mlb[w * 32 + lm]        = M[0];
    mlb[w * 32 + 16 + lm]   = M[1];
    mlb[256 + w * 32 + lm]      = L[0];
    mlb[256 + w * 32 + 16 + lm] = L[1];
  }
#undef STAGE
#undef BLOAD
}

// ---------------------------------------------------------------------------
// Combine the two kv-half partials -> comb bf16 [B*S][D].
// Block = one (p, w) pair: 32 q x 64 d. Reads lane-major OP coalesced,
// fixes (q,d) order through a small LDS transpose, stores coalesced.
// ---------------------------------------------------------------------------
__global__ __launch_bounds__(256)
void combine(const float* __restrict__ OP, const float* __restrict__ ML,
             short* __restrict__ comb) {
  const int w = blockIdx.x & 7, p = blockIdx.x >> 3;   // p in [0,256)
  const int b = p >> 7, h = (p >> 3) & 15, qb = p & 7;
  const int t = threadIdx.x, lane = t & 63, fr2 = t >> 6;  // fr2 in [0,4)
  __shared__ __attribute__((aligned(16))) short tile[32 * 72];
  const float* op0 = OP + (size_t)p * 16384 + w * 2048;
  const float* op1 = OP + (size_t)(256 + p) * 16384 + w * 2048;
  const float* ml0 = ML + (size_t)p * 512;
  const float* ml1 = ML + (size_t)(256 + p) * 512;
  #pragma unroll
  for (int ff = 0; ff < 2; ++ff) {
    int f = fr2 + ff * 4, fq = f >> 2, of = f & 3;
    int ql = fq * 16 + (lane & 15);          // q in [0,32)
    int d  = of * 16 + (lane >> 4) * 4;
    float m0 = ml0[w * 32 + ql], m1 = ml1[w * 32 + ql];
    float l0 = ml0[256 + w * 32 + ql], l1 = ml1[256 + w * 32 + ql];
    float m = fmaxf(m0, m1);
    float a0 = exp2f(m0 - m), a1 = exp2f(m1 - m);
    float inv = 1.f / (l0 * a0 + l1 * a1);
    f32x4 v0 = *(const f32x4*)&op0[f * 256 + lane * 4];
    f32x4 v1 = *(const f32x4*)&op1[f * 256 + lane * 4];
    s16x4 r;
    #pragma unroll
    for (int j = 0; j < 4; ++j)
      r[j] = f2bf((v0[j] * a0 + v1[j] * a1) * inv);
    *(s16x4*)&tile[ql * 72 + d] = r;
  }
  __syncthreads();
  const int row = t >> 3, seg = t & 7;
  u32x4 u = *(const u32x4*)&tile[row * 72 + seg * 8];
  *(u32x4*)&comb[((size_t)(b * S + qb * 256 + w * 32 + row)) * D + h * HD + seg * 8] = u;
}

// ---------------------------------------------------------------------------
// w_out [k][n] f32 -> Wt [n][k] bf16
// ---------------------------------------------------------------------------
__global__ __launch_bounds__(256)
void wt_kernel(const float* __restrict__ W, short* __restrict__ Wt) {
  __shared__ __attribute__((aligned(16))) short tile[64 * 72];
  const int n0 = blockIdx.x * 64, k0 = blockIdx.y * 64;
  const int t = threadIdx.x;
  #pragma unroll
  for (int i = 0; i < 4; ++i) {
    int idx = i * 256 + t;
    int r  = idx >> 4, c4 = (idx & 15) * 4;
    float4 wv = *(const float4*)(W + (size_t)(k0 + r) * D + n0 + c4);
    tile[(c4 + 0) * 72 + r] = f2bf(wv.x);
    tile[(c4 + 1) * 72 + r] = f2bf(wv.y);
    tile[(c4 + 2) * 72 + r] = f2bf(wv.z);
    tile[(c4 + 3) * 72 + r] = f2bf(wv.w);
  }
  __syncthreads();
  #pragma unroll
  for (int it = 0; it < 2; ++it) {
    int idx = it * 256 + t;
    int r = idx >> 3, seg = idx & 7;
    u32x4 u = *(const u32x4*)&tile[r * 72 + seg * 8];
    *(u32x4*)&Wt[(size_t)(n0 + r) * D + k0 + seg * 8] = u;
  }
}

// ---------------------------------------------------------------------------
// proj: C[4096,1024] f32 = A bf16 * Wt^T. 128x64 tile, counted-vmcnt,
// both-sides 16B-unit XOR swizzle on LDS.
// ---------------------------------------------------------------------------
__device__ __forceinline__ bf16x8 ld_frag_swz(const short* base, int row, int kk, int lg) {
  const char* rp = (const char*)base + row * 128 + (lg & 1) * 8;
  int u0 = kk * 4 + (lg >> 1);
  int f  = row & 7;
  s16x4 c0 = *(const s16x4*)(rp + ((u0 ^ f) << 4));
  s16x4 c1 = *(const s16x4*)(rp + (((u0 + 2) ^ f) << 4));
  bf16x8 a;
  a[0]=c0[0]; a[1]=c0[1]; a[2]=c0[2]; a[3]=c0[3];
  a[4]=c1[0]; a[5]=c1[1]; a[6]=c1[2]; a[7]=c1[3];
  return a;
}

__global__ __launch_bounds__(256, 2)
void proj_gemm(const short* __restrict__ A, const short* __restrict__ Bt,
               float* __restrict__ C) {
  __shared__ __attribute__((aligned(16))) short a_lds[2][8192];
  __shared__ __attribute__((aligned(16))) short b_lds[2][4096];
  const int m0 = blockIdx.x * 128, n0 = blockIdx.y * 64;
  const int t = threadIdx.x, lane = t & 63, w = t >> 6;
  const int lg = lane >> 4, lm = lane & 15;
  const int srow = lane >> 3;
  const int sunit = (lane & 7) ^ srow;

  const f32x4 zero4 = {0.f, 0.f, 0.f, 0.f};
  f32x4 acc[2][4];
  #pragma unroll
  for (int i = 0; i < 2; ++i)
    #pragma unroll
    for (int j = 0; j < 4; ++j) acc[i][j] = zero4;

#define PSTAGE(ks, ab, bb)                                                  \
  {                                                                         \
    const short* ag_ = A  + (size_t)m0 * D + (ks) * 64;                     \
    const short* bg_ = Bt + (size_t)n0 * D + (ks) * 64;                     \
    _Pragma("unroll")                                                       \
    for (int i_ = 0; i_ < 4; ++i_) {                                        \
      int j_ = w * 4 + i_;                                                  \
      GLDS16(ag_ + (size_t)(j_ * 8 + srow) * D + sunit * 8, (ab) + j_ * 512); \
    }                                                                       \
    _Pragma("unroll")                                                       \
    for (int i_ = 0; i_ < 2; ++i_) {                                        \
      int j_ = w * 2 + i_;                                                  \
      GLDS16(bg_ + (size_t)(j_ * 8 + srow) * D + sunit * 8, (bb) + j_ * 512); \
    }                                                                       \
  }

#define PCOMPUTE(ab, bb)                                                    \
  {                                                                         \
    _Pragma("unroll")                                                       \
    for (int kk = 0; kk < 2; ++kk) {                                        \
      bf16x8 af0 = ld_frag_swz(ab, w * 32 + lm, kk, lg);                    \
      bf16x8 af1 = ld_frag_swz(ab, w * 32 + 16 + lm, kk, lg);               \
      bf16x8 bf0 = ld_frag_swz(bb, lm, kk, lg);                             \
      bf16x8 bf1 = ld_frag_swz(bb, 16 + lm, kk, lg);                        \
      bf16x8 bf2 = ld_frag_swz(bb, 32 + lm, kk, lg);                        \
      bf16x8 bf3 = ld_frag_swz(bb, 48 + lm, kk, lg);                        \
      __builtin_amdgcn_s_setprio(1);                                        \
      acc[0][0] = MFMA_BF16(af0, bf0, acc[0][0], 0, 0, 0);                  \
      acc[0][1] = MFMA_BF16(af0, bf1, acc[0][1], 0, 0, 0);                  \
      acc[0][2] = MFMA_BF16(af0, bf2, acc[0][2], 0, 0, 0);                  \
      acc[0][3] = MFMA_BF16(af0, bf3, acc[0][3], 0, 0, 0);                  \
      acc[1][0] = MFMA_BF16(af1, bf0, acc[1][0], 0, 0, 0);                  \
      acc[1][1] = MFMA_BF16(af1, bf1, acc[1][1], 0, 0, 0);                  \
      acc[1][2] = MFMA_BF16(af1, bf2, acc[1][2], 0, 0, 0);                  \
      acc[1][3] = MFMA_BF16(af1, bf3, acc[1][3], 0, 0, 0);                  \
      __builtin_amdgcn_s_setprio(0);                                        \
    }                                                                       \
  }

  PSTAGE(0, a_lds[0], b_lds[0]);
  for (int ks = 0; ks < 16; ks += 2) {
    SBAR();
    PSTAGE(ks + 1, a_lds[1], b_lds[1]);
    WAITV(6);
    SBAR();
    PCOMPUTE(a_lds[0], b_lds[0]);
    SBAR();
    if (ks + 2 < 16) {
      PSTAGE(ks + 2, a_lds[0], b_lds[0]);
      WAITV(6);
    } else {
      WAITV(0);
    }
    SBAR();
    PCOMPUTE(a_lds[1], b_lds[1]);
  }

  #pragma unroll
  for (int mf = 0; mf < 2; ++mf)
    #pragma unroll
    for (int j = 0; j < 4; ++j)
      #pragma unroll
      for (int nf = 0; nf < 4; ++nf)
        C[(size_t)(m0 + w * 32 + mf * 16 + lg * 4 + j) * D +
          n0 + nf * 16 + lm] = acc[mf][nf][j];
#undef PSTAGE
#undef PCOMPUTE
}

extern "C" void kernel_launch(void* const* d_in, const int* in_sizes, int n_in,
                              void* d_out, int out_size, void* d_ws, size_t ws_size,
                              hipStream_t stream) {
  const float* Qg = (const float*)d_in[0];
  const float* Kg = (const float*)d_in[1];
  const float* Vg = (const float*)d_in[2];
  const float* Bg = (const float*)d_in[3];
  const float* Wg = (const float*)d_in[4];
  float* out = (float*)d_out;

  short* comb = (short*)d_ws;                          //  8.4 MB bf16 [4096][1024]
  short* Wt   = comb + (size_t)4096 * 1024;            //  2.1 MB bf16 [1024][1024]
  short* KVb  = Wt   + (size_t)1024 * 1024;            // 16.8 MB interleaved K/V frags
  float* OP   = (float*)(KVb + (size_t)2 * H * NT * 8192); // 33.6 MB lane-major partial O
  float* ML   = OP + (size_t)2 * 256 * 16384;              //  1.1 MB m,l

  kv_prep<<<dim3(NT, H, 2), 256, 0, stream>>>(Kg, Vg, KVb);
  wt_kernel<<<dim3(D / 64, D / 64), 256, 0, stream>>>(Wg, Wt);
  attn_fused<<<dim3(512), 512, 0, stream>>>(Qg, Bg, KVb, OP, ML);
  combine<<<dim3(2048), 256, 0, stream>>>(OP, ML, comb);
  proj_gemm<<<dim3(32, 16), 256, 0, stream>>>(comb, Wt, out);
}